// Round 17
// baseline (337.108 us; speedup 1.0000x reference)
//
#include <hip/hip_runtime.h>
#include <hip/hip_bf16.h>

// GraphSAGE 2-layer. R17: CSR chain (hist/scan/scatter) folded INTO the gemm
// dispatch as block roles ordered by spin barriers -> overlaps the 160us
// latency-bound GEMM. 4 dispatches total.
// Ledger: gemm 160us (ceiling), aggs ~50us (random-line ceiling), rest now
// mostly hidden.

typedef __attribute__((ext_vector_type(8))) __bf16 bf16x8;
typedef __attribute__((ext_vector_type(4))) float f32x4;

constexpr int K1 = 1433;
constexpr int KP1 = 1536;
constexpr int BK = 32;
constexpr int NS = 45;
constexpr int BM = 128;
constexpr int CONV_BLOCKS = (64 * KP1 + 64 * 32 + 255) / 256;  // 392
constexpr int HIST_BLOCKS = 192;
constexpr int SCAT_BLOCKS = 128;

__device__ __forceinline__ void gload_lds16(const void* g, void* l) {
  __builtin_amdgcn_global_load_lds(
      reinterpret_cast<const __attribute__((address_space(1))) void*>(
          reinterpret_cast<uintptr_t>(g)),
      reinterpret_cast<__attribute__((address_space(3))) void*>(
          reinterpret_cast<uintptr_t>(l)),
      16, 0, 0);
}

__device__ __forceinline__ bf16x8 cvt8(const float4 lo, const float4 hi) {
  bf16x8 r;
  r[0] = (__bf16)lo.x; r[1] = (__bf16)lo.y;
  r[2] = (__bf16)lo.z; r[3] = (__bf16)lo.w;
  r[4] = (__bf16)hi.x; r[5] = (__bf16)hi.y;
  r[6] = (__bf16)hi.z; r[7] = (__bf16)hi.w;
  return r;
}

// conv blocks convert weights; zero-role blocks clear deg|fill|counters.
__global__ __launch_bounds__(256) void conv_zero(
    const float* __restrict__ W1l, const float* __restrict__ W1r,
    const float* __restrict__ W2l, const float* __restrict__ W2r,
    __bf16* __restrict__ wb1, __bf16* __restrict__ wb2,
    int* __restrict__ zbuf, int zcount) {
  if ((int)blockIdx.x < CONV_BLOCKS) {
    const int t = blockIdx.x * 256 + threadIdx.x;
    if (t < 64 * KP1) {
      const int c = t / KP1, k = t - c * KP1;
      float v = 0.0f;
      if (k < K1)
        v = (c < 32) ? W1l[(long)c * K1 + k] : W1r[(long)(c - 32) * K1 + k];
      wb1[t] = (__bf16)v;
    } else {
      const int u = t - 64 * KP1;
      if (u < 64 * 32) {
        const int c = u >> 5, k = u & 31;
        const float v = (c < 32) ? W2l[c * 32 + k] : W2r[(c - 32) * 32 + k];
        wb2[u] = (__bf16)v;
      }
    }
  } else {
    const int base = (blockIdx.x - CONV_BLOCKS) * 4096 + threadIdx.x * 16;
#pragma unroll
    for (int j = 0; j < 16; ++j) {
      const int i = base + j;
      if (i < zcount) zbuf[i] = 0;
    }
  }
}

// Mega-dispatch: block roles by ID. [0,H): hist -> arrive cntH.
// [H,H+SC): scan (spin cntH) -> internal cntS barrier -> off -> arrive cntO.
// [H+SC,H+SC+T): scatter (spin cntO). Rest: the R8 GEMM (no deps).
// cnts = {cntH, cntS, cntO}, zeroed by conv_zero each launch.
__global__ __launch_bounds__(256) void gemm_fused(
    const float* __restrict__ X, const __bf16* __restrict__ WB,
    __bf16* __restrict__ yl, float* __restrict__ yr, int Nrows,
    const int* __restrict__ ei, int* __restrict__ deg, int E,
    int* __restrict__ off, int* __restrict__ fill, int* __restrict__ ssrc,
    int* __restrict__ tileSum, int* __restrict__ cnts, int nT) {
  __shared__ float ldsA[2][BM][BK];
  __shared__ __bf16 ldsB[2][64][BK];
  __shared__ int warpTot[4];
  __shared__ int tileOffS;
  const int bid = blockIdx.x;
  const int tid = threadIdx.x;
  const int roleEnd = HIST_BLOCKS + nT + SCAT_BLOCKS;

  if (bid < HIST_BLOCKS) {  // ---------------- hist ----------------
    for (int e = bid * 256 + tid; e < E; e += HIST_BLOCKS * 256)
      atomicAdd(&deg[ei[E + e]], 1);
    __threadfence();
    __syncthreads();
    if (tid == 0) atomicAdd(&cnts[0], 1);
    return;
  }
  if (bid < HIST_BLOCKS + nT) {  // ------------- scan -------------
    const int b = bid - HIST_BLOCKS;
    if (tid == 0) {
      while (__hip_atomic_load(&cnts[0], __ATOMIC_ACQUIRE,
                               __HIP_MEMORY_SCOPE_AGENT) < HIST_BLOCKS) {
        __builtin_amdgcn_s_sleep(2);
      }
    }
    __syncthreads();  // deg fully built beyond this point
    const int base = b * 2048 + tid * 8;
    int v[8];
    int s = 0;
#pragma unroll
    for (int j = 0; j < 8; ++j) {
      const int i = base + j;
      v[j] = (i < Nrows) ? deg[i] : 0;
      s += v[j];
    }
    const int l = tid & 63, w = tid >> 6;
    int inc = s;
#pragma unroll
    for (int d = 1; d < 64; d <<= 1) {
      const int o = __shfl_up(inc, d);
      if (l >= d) inc += o;
    }
    if (l == 63) warpTot[w] = inc;
    __syncthreads();
    const int blockTot = warpTot[0] + warpTot[1] + warpTot[2] + warpTot[3];
    int wo = 0;
    for (int k = 0; k < w; ++k) wo += warpTot[k];
    if (tid == 0) {
      __hip_atomic_store(&tileSum[b], blockTot, __ATOMIC_RELEASE,
                         __HIP_MEMORY_SCOPE_AGENT);
      atomicAdd(&cnts[1], 1);
      while (__hip_atomic_load(&cnts[1], __ATOMIC_ACQUIRE,
                               __HIP_MEMORY_SCOPE_AGENT) < nT) {
        __builtin_amdgcn_s_sleep(2);
      }
    }
    __syncthreads();
    int tv = 0;
    if (tid < 64) {
      int x2 = (tid < b) ? __hip_atomic_load(&tileSum[tid], __ATOMIC_ACQUIRE,
                                             __HIP_MEMORY_SCOPE_AGENT)
                         : 0;
#pragma unroll
      for (int d = 1; d < 64; d <<= 1) x2 += __shfl_xor(x2, d);
      tv = x2;
    }
    if (tid == 0) tileOffS = tv;
    __syncthreads();
    int ex = tileOffS + wo + (inc - s);
#pragma unroll
    for (int j = 0; j < 8; ++j) {
      const int i = base + j;
      if (i < Nrows) {
        off[i] = ex;
        ex += v[j];
      }
    }
    __threadfence();
    __syncthreads();
    if (tid == 0) atomicAdd(&cnts[2], 1);
    return;
  }
  if (bid < roleEnd) {  // ---------------- scatter ----------------
    if (tid == 0) {
      while (__hip_atomic_load(&cnts[2], __ATOMIC_ACQUIRE,
                               __HIP_MEMORY_SCOPE_AGENT) < nT) {
        __builtin_amdgcn_s_sleep(2);
      }
    }
    __syncthreads();  // off fully published
    const int sb = bid - HIST_BLOCKS - nT;
    for (int e = sb * 256 + tid; e < E; e += SCAT_BLOCKS * 256) {
      const int t = ei[E + e];
      const int p = off[t] + atomicAdd(&fill[t], 1);
      ssrc[p] = ei[e];
    }
    return;
  }

  // ---------------- gemm role (R8 pipeline, unchanged) ----------------
  const int w = tid >> 6, l = tid & 63;
  const int lr = l & 15, lg = l >> 4;
  const int row0 = (bid - roleEnd) * BM;

  const int aRowIn = (l >> 3);
  const int aChunk = (l & 7) ^ aRowIn;
  long aRow[4];
#pragma unroll
  for (int i = 0; i < 4; ++i) {
    long r = (long)row0 + w * 32 + i * 8 + aRowIn;
    if (r >= Nrows) r = Nrows - 1;
    aRow[i] = r;
  }
  const float* const pAmax = X + (size_t)Nrows * K1 - 4;
  const int bRow = w * 16 + (l >> 2);
  const int bChunk = (l & 3) ^ ((l >> 3) & 3);
  const __bf16* const pB0 = WB + (long)bRow * KP1 + bChunk * 8;

  auto stage = [&](int s, int buf) {
    const int k0 = s * BK;
#pragma unroll
    for (int i = 0; i < 4; ++i) {
      const float* g = X + aRow[i] * K1 + k0 + aChunk * 4;
      if (g > pAmax) g = pAmax;
      gload_lds16(g, &ldsA[buf][w * 32 + i * 8][0]);
    }
    gload_lds16(pB0 + k0, &ldsB[buf][w * 16][0]);
  };

  f32x4 acc[2][4];
#pragma unroll
  for (int t = 0; t < 2; ++t)
#pragma unroll
    for (int j = 0; j < 4; ++j) acc[t][j] = (f32x4){0.f, 0.f, 0.f, 0.f};

  const int swzA = lr & 7;
  const int swzB = (lr >> 1) & 3;

  stage(0, 0);
#pragma unroll 1
  for (int s = 0; s < NS; ++s) {
    const int buf = s & 1;
    if (s + 1 < NS) {
      stage(s + 1, buf ^ 1);
      asm volatile("s_waitcnt vmcnt(5)" ::: "memory");
    } else {
      asm volatile("s_waitcnt vmcnt(0)" ::: "memory");
    }
    __builtin_amdgcn_s_barrier();
    __builtin_amdgcn_sched_barrier(0);
    bf16x8 bfrag[4];
#pragma unroll
    for (int ct = 0; ct < 4; ++ct) {
      const int br = ct * 16 + lr;
      bfrag[ct] = *reinterpret_cast<const bf16x8*>(
          &ldsB[buf][br][(lg ^ swzB) * 8]);
    }
#pragma unroll
    for (int t = 0; t < 2; ++t) {
      const int fr = w * 32 + t * 16 + lr;
      const float4 u = *reinterpret_cast<const float4*>(
          &ldsA[buf][fr][((lg * 2 + 0) ^ swzA) * 4]);
      const float4 v = *reinterpret_cast<const float4*>(
          &ldsA[buf][fr][((lg * 2 + 1) ^ swzA) * 4]);
      const bf16x8 af = cvt8(u, v);
#pragma unroll
      for (int ct = 0; ct < 4; ++ct)
        acc[t][ct] =
            __builtin_amdgcn_mfma_f32_16x16x32_bf16(af, bfrag[ct], acc[t][ct], 0, 0, 0);
    }
    __builtin_amdgcn_sched_barrier(0);
    __builtin_amdgcn_s_barrier();
  }

#pragma unroll
  for (int t = 0; t < 2; ++t) {
#pragma unroll
    for (int j = 0; j < 4; ++j) {
      const long R = (long)row0 + w * 32 + t * 16 + lg * 4 + j;
      if (R < Nrows) {
#pragma unroll
        for (int ct = 0; ct < 2; ++ct)
          yl[R * 32 + ct * 16 + lr] = (__bf16)acc[t][ct][j];
#pragma unroll
        for (int ct = 2; ct < 4; ++ct)
          yr[R * 32 + (ct - 2) * 16 + lr] = acc[t][ct][j];
      }
    }
  }
}

// ---- fused layer-1 tail: bf16-gather agg -> h (LDS) -> h @ W2^T ----
__global__ __launch_bounds__(256) void agg_gemm2(
    const int* __restrict__ off, const int* __restrict__ deg,
    const int* __restrict__ ssrc, const __bf16* __restrict__ yl1,
    const float* __restrict__ yr1, const float* __restrict__ b1,
    const __bf16* __restrict__ WB2, __bf16* __restrict__ yl2,
    float* __restrict__ yr2, int N) {
  __shared__ __bf16 hs[64][40];
  const int tid = threadIdx.x;
  const int nb0 = blockIdx.x * 64;
  const int c = tid & 31, r8 = tid >> 5;

  int stA[8], dgA[8];
#pragma unroll
  for (int j = 0; j < 8; ++j) {
    const int i = nb0 + r8 * 8 + j;
    stA[j] = (i < N) ? off[i] : 0;
    dgA[j] = (i < N) ? deg[i] : 0;
  }
#pragma unroll 1
  for (int j = 0; j < 8; ++j) {
    const int i = nb0 + r8 * 8 + j;
    float hv = 0.0f;
    if (i < N) {
      const int st = stA[j], d = dgA[j];
      float acc = 0.0f;
      int e = 0;
      for (; e + 4 <= d; e += 4) {
        const int s0 = ssrc[st + e + 0];
        const int s1 = ssrc[st + e + 1];
        const int s2 = ssrc[st + e + 2];
        const int s3 = ssrc[st + e + 3];
        acc += (float)yl1[(long)s0 * 32 + c] + (float)yl1[(long)s1 * 32 + c] +
               (float)yl1[(long)s2 * 32 + c] + (float)yl1[(long)s3 * 32 + c];
      }
      for (; e < d; ++e) acc += (float)yl1[(long)ssrc[st + e] * 32 + c];
      hv = acc / fmaxf((float)d, 1.0f) + b1[c] + yr1[(long)i * 32 + c];
    }
    hs[r8 * 8 + j][c] = (__bf16)hv;
  }
  __syncthreads();

  const int w = tid >> 6, l = tid & 63;
  const int lr = l & 15, lg = l >> 4;
  const bf16x8 af = *reinterpret_cast<const bf16x8*>(&hs[w * 16 + lr][lg * 8]);
  f32x4 acc4[4];
#pragma unroll
  for (int j = 0; j < 4; ++j) acc4[j] = (f32x4){0.f, 0.f, 0.f, 0.f};
#pragma unroll
  for (int ct = 0; ct < 4; ++ct) {
    const bf16x8 bf = *reinterpret_cast<const bf16x8*>(
        WB2 + (ct * 16 + lr) * 32 + lg * 8);
    acc4[ct] = __builtin_amdgcn_mfma_f32_16x16x32_bf16(af, bf, acc4[ct], 0, 0, 0);
  }
#pragma unroll
  for (int j = 0; j < 4; ++j) {
    const long R = (long)nb0 + w * 16 + lg * 4 + j;
    if (R < N) {
#pragma unroll
      for (int ct = 0; ct < 2; ++ct)
        yl2[R * 32 + ct * 16 + lr] = (__bf16)acc4[ct][j];
#pragma unroll
      for (int ct = 2; ct < 4; ++ct)
        yr2[R * 32 + (ct - 2) * 16 + lr] = acc4[ct][j];
    }
  }
}

// -------- layer-2 tail: bf16-gather agg + relu + log_softmax --------
__global__ __launch_bounds__(256) void agg_final(
    const int* __restrict__ off, const int* __restrict__ deg,
    const int* __restrict__ ssrc, const __bf16* __restrict__ yl2,
    const float* __restrict__ yr2, const float* __restrict__ bias,
    float* __restrict__ out, int N) {
  const int t = blockIdx.x * 256 + threadIdx.x;
  const int i = t >> 5, c = t & 31;
  if (i >= N) return;
  const int st = off[i], d = deg[i];
  float acc = 0.0f;
  int e = 0;
  for (; e + 4 <= d; e += 4) {
    const int s0 = ssrc[st + e + 0];
    const int s1 = ssrc[st + e + 1];
    const int s2 = ssrc[st + e + 2];
    const int s3 = ssrc[st + e + 3];
    acc += (float)yl2[(long)s0 * 32 + c] + (float)yl2[(long)s1 * 32 + c] +
           (float)yl2[(long)s2 * 32 + c] + (float)yl2[(long)s3 * 32 + c];
  }
  for (; e < d; ++e) acc += (float)yl2[(long)ssrc[st + e] * 32 + c];
  const float mean = acc / fmaxf((float)d, 1.0f);
  float v = mean + bias[c] + yr2[(long)i * 32 + c];
  v = fmaxf(v, 0.0f);
  float m = v;
#pragma unroll
  for (int dd = 16; dd >= 1; dd >>= 1) m = fmaxf(m, __shfl_xor(m, dd));
  const float ex = __expf(v - m);
  float s = ex;
#pragma unroll
  for (int dd = 16; dd >= 1; dd >>= 1) s += __shfl_xor(s, dd);
  out[(long)i * 32 + c] = (v - m) - __logf(s);
}

extern "C" void kernel_launch(void* const* d_in, const int* in_sizes, int n_in,
                              void* d_out, int out_size, void* d_ws,
                              size_t ws_size, hipStream_t stream) {
  const float* x = (const float*)d_in[0];
  const int* ei = (const int*)d_in[1];
  const float* W1l = (const float*)d_in[2];
  const float* b1l = (const float*)d_in[3];
  const float* W1r = (const float*)d_in[4];
  const float* W2l = (const float*)d_in[5];
  const float* b2l = (const float*)d_in[6];
  const float* W2r = (const float*)d_in[7];
  float* out = (float*)d_out;

  const int N = in_sizes[0] / K1;
  const int E = in_sizes[1] / 2;
  const int nTiles = (N + 2047) / 2048;  // 49 at N=100000

  char* ws = (char*)d_ws;
  size_t o = 0;
  auto alloc = [&](size_t bytes) {
    void* p = ws + o;
    o += (bytes + 255) & ~(size_t)255;
    return p;
  };
  __bf16* yl1 = (__bf16*)alloc((size_t)N * 32 * 2);
  float* yr1 = (float*)alloc((size_t)N * 32 * 4);
  __bf16* yl2 = (__bf16*)alloc((size_t)N * 32 * 2);
  float* yr2 = (float*)alloc((size_t)N * 32 * 4);
  __bf16* wb1 = (__bf16*)alloc((size_t)64 * KP1 * 2);
  __bf16* wb2 = (__bf16*)alloc((size_t)64 * 32 * 2);
  int* deg = (int*)alloc((size_t)(2 * N + 64) * 4);  // deg | fill | cnts
  int* fill = deg + N;
  int* cnts = deg + 2 * N;
  int* off = (int*)alloc((size_t)N * 4);
  int* ssrc = (int*)alloc((size_t)E * 4);
  int* tileSum = (int*)alloc(64 * 4);

  const int zcount = 2 * N + 64;
  const int zBlocks = (zcount + 4095) / 4096;
  conv_zero<<<CONV_BLOCKS + zBlocks, 256, 0, stream>>>(W1l, W1r, W2l, W2r,
                                                       wb1, wb2, deg, zcount);
  const int gemmBlocks = (N + BM - 1) / BM;
  const int roleBlocks = HIST_BLOCKS + nTiles + SCAT_BLOCKS;
  gemm_fused<<<roleBlocks + gemmBlocks, 256, 0, stream>>>(
      x, wb1, yl1, yr1, N, ei, deg, E, off, fill, ssrc, tileSum, cnts,
      nTiles);
  agg_gemm2<<<(N + 63) / 64, 256, 0, stream>>>(off, deg, ssrc, yl1, yr1, b1l,
                                               wb2, yl2, yr2, N);
  agg_final<<<(N * 32 + 255) / 256, 256, 0, stream>>>(off, deg, ssrc, yl2,
                                                      yr2, b2l, out, N);
}

// Round 18
// 292.012 us; speedup vs baseline: 1.1544x; 1.1544x over previous
//
#include <hip/hip_runtime.h>
#include <hip/hip_bf16.h>

// GraphSAGE 2-layer. R18 = R16 (best, 265.9us) + csr_scan/scatter merged into
// one dispatch (scan roles -> spin barrier -> scatter roles; no gemm overlap,
// R17's contention lesson applied). 5 dispatches total.
// Ledger: gemm 160us (read-path ceiling), aggs ~50us (L2 line-touch ceiling),
// CSR+conv+gaps ~45us.

typedef __attribute__((ext_vector_type(8))) __bf16 bf16x8;
typedef __attribute__((ext_vector_type(4))) float f32x4;

constexpr int K1 = 1433;
constexpr int KP1 = 1536;
constexpr int BK = 32;
constexpr int NS = 45;
constexpr int BM = 128;
constexpr int CONV_BLOCKS = (64 * KP1 + 64 * 32 + 255) / 256;  // 392
constexpr int SCAT_BLOCKS = 128;

__device__ __forceinline__ void gload_lds16(const void* g, void* l) {
  __builtin_amdgcn_global_load_lds(
      reinterpret_cast<const __attribute__((address_space(1))) void*>(
          reinterpret_cast<uintptr_t>(g)),
      reinterpret_cast<__attribute__((address_space(3))) void*>(
          reinterpret_cast<uintptr_t>(l)),
      16, 0, 0);
}

__device__ __forceinline__ bf16x8 cvt8(const float4 lo, const float4 hi) {
  bf16x8 r;
  r[0] = (__bf16)lo.x; r[1] = (__bf16)lo.y;
  r[2] = (__bf16)lo.z; r[3] = (__bf16)lo.w;
  r[4] = (__bf16)hi.x; r[5] = (__bf16)hi.y;
  r[6] = (__bf16)hi.z; r[7] = (__bf16)hi.w;
  return r;
}

// conv blocks convert weights; zero-role blocks clear deg|fill|counters.
__global__ __launch_bounds__(256) void conv_zero(
    const float* __restrict__ W1l, const float* __restrict__ W1r,
    const float* __restrict__ W2l, const float* __restrict__ W2r,
    __bf16* __restrict__ wb1, __bf16* __restrict__ wb2,
    int* __restrict__ zbuf, int zcount) {
  if ((int)blockIdx.x < CONV_BLOCKS) {
    const int t = blockIdx.x * 256 + threadIdx.x;
    if (t < 64 * KP1) {
      const int c = t / KP1, k = t - c * KP1;
      float v = 0.0f;
      if (k < K1)
        v = (c < 32) ? W1l[(long)c * K1 + k] : W1r[(long)(c - 32) * K1 + k];
      wb1[t] = (__bf16)v;
    } else {
      const int u = t - 64 * KP1;
      if (u < 64 * 32) {
        const int c = u >> 5, k = u & 31;
        const float v = (c < 32) ? W2l[c * 32 + k] : W2r[(c - 32) * 32 + k];
        wb2[u] = (__bf16)v;
      }
    }
  } else {
    const int base = (blockIdx.x - CONV_BLOCKS) * 4096 + threadIdx.x * 16;
#pragma unroll
    for (int j = 0; j < 16; ++j) {
      const int i = base + j;
      if (i < zcount) zbuf[i] = 0;
    }
  }
}

// yl[N][32] (bf16) | yr[N][32] (f32) = X @ WB^T.  (R8 pipeline.)
// Blocks >= gemmBlocks do the degree histogram (hidden under the GEMM).
__global__ __launch_bounds__(256) void gemm_big(const float* __restrict__ X,
                                                const __bf16* __restrict__ WB,
                                                __bf16* __restrict__ yl,
                                                float* __restrict__ yr,
                                                int Nrows, int gemmBlocks,
                                                const int* __restrict__ ei,
                                                int* __restrict__ deg, int E) {
  __shared__ float ldsA[2][BM][BK];
  __shared__ __bf16 ldsB[2][64][BK];
  if ((int)blockIdx.x >= gemmBlocks) {  // ---- hist role ----
    const int base = ((int)blockIdx.x - gemmBlocks) * 1024 + threadIdx.x;
#pragma unroll
    for (int j = 0; j < 4; ++j) {
      const int e = base + j * 256;
      if (e < E) atomicAdd(&deg[ei[E + e]], 1);
    }
    return;
  }
  const int tid = threadIdx.x;
  const int w = tid >> 6, l = tid & 63;
  const int lr = l & 15, lg = l >> 4;
  const int row0 = blockIdx.x * BM;

  const int aRowIn = (l >> 3);
  const int aChunk = (l & 7) ^ aRowIn;
  long aRow[4];
#pragma unroll
  for (int i = 0; i < 4; ++i) {
    long r = (long)row0 + w * 32 + i * 8 + aRowIn;
    if (r >= Nrows) r = Nrows - 1;
    aRow[i] = r;
  }
  const float* const pAmax = X + (size_t)Nrows * K1 - 4;
  const int bRow = w * 16 + (l >> 2);
  const int bChunk = (l & 3) ^ ((l >> 3) & 3);
  const __bf16* const pB0 = WB + (long)bRow * KP1 + bChunk * 8;

  auto stage = [&](int s, int buf) {
    const int k0 = s * BK;
#pragma unroll
    for (int i = 0; i < 4; ++i) {
      const float* g = X + aRow[i] * K1 + k0 + aChunk * 4;
      if (g > pAmax) g = pAmax;
      gload_lds16(g, &ldsA[buf][w * 32 + i * 8][0]);
    }
    gload_lds16(pB0 + k0, &ldsB[buf][w * 16][0]);
  };

  f32x4 acc[2][4];
#pragma unroll
  for (int t = 0; t < 2; ++t)
#pragma unroll
    for (int j = 0; j < 4; ++j) acc[t][j] = (f32x4){0.f, 0.f, 0.f, 0.f};

  const int swzA = lr & 7;
  const int swzB = (lr >> 1) & 3;

  stage(0, 0);
#pragma unroll 1
  for (int s = 0; s < NS; ++s) {
    const int buf = s & 1;
    if (s + 1 < NS) {
      stage(s + 1, buf ^ 1);
      asm volatile("s_waitcnt vmcnt(5)" ::: "memory");
    } else {
      asm volatile("s_waitcnt vmcnt(0)" ::: "memory");
    }
    __builtin_amdgcn_s_barrier();
    __builtin_amdgcn_sched_barrier(0);
    bf16x8 bfrag[4];
#pragma unroll
    for (int ct = 0; ct < 4; ++ct) {
      const int br = ct * 16 + lr;
      bfrag[ct] = *reinterpret_cast<const bf16x8*>(
          &ldsB[buf][br][(lg ^ swzB) * 8]);
    }
#pragma unroll
    for (int t = 0; t < 2; ++t) {
      const int fr = w * 32 + t * 16 + lr;
      const float4 u = *reinterpret_cast<const float4*>(
          &ldsA[buf][fr][((lg * 2 + 0) ^ swzA) * 4]);
      const float4 v = *reinterpret_cast<const float4*>(
          &ldsA[buf][fr][((lg * 2 + 1) ^ swzA) * 4]);
      const bf16x8 af = cvt8(u, v);
#pragma unroll
      for (int ct = 0; ct < 4; ++ct)
        acc[t][ct] =
            __builtin_amdgcn_mfma_f32_16x16x32_bf16(af, bfrag[ct], acc[t][ct], 0, 0, 0);
    }
    __builtin_amdgcn_sched_barrier(0);
    __builtin_amdgcn_s_barrier();
  }

#pragma unroll
  for (int t = 0; t < 2; ++t) {
#pragma unroll
    for (int j = 0; j < 4; ++j) {
      const long R = (long)row0 + w * 32 + t * 16 + lg * 4 + j;
      if (R < Nrows) {
#pragma unroll
        for (int ct = 0; ct < 2; ++ct)
          yl[R * 32 + ct * 16 + lr] = (__bf16)acc[t][ct][j];
#pragma unroll
        for (int ct = 2; ct < 4; ++ct)
          yr[R * 32 + (ct - 2) * 16 + lr] = acc[t][ct][j];
      }
    }
  }
}

// ---- merged CSR build: scan roles [0,nT) then scatter roles [nT,nT+128) ----
// cnts[0]: scan internal tileSum barrier; cnts[1]: off published.
// 177 low-LDS blocks: all co-resident; dependency order == dispatch order.
__global__ __launch_bounds__(256) void csr_build(
    const int* __restrict__ deg, int* __restrict__ tileSum,
    int* __restrict__ cnts, int* __restrict__ off, int n, int nT,
    const int* __restrict__ ei, int* __restrict__ fill,
    int* __restrict__ ssrc, int E) {
  const int bid = blockIdx.x, t = threadIdx.x;
  if (bid >= nT) {  // ---------------- scatter role ----------------
    if (t == 0) {
      while (__hip_atomic_load(&cnts[1], __ATOMIC_ACQUIRE,
                               __HIP_MEMORY_SCOPE_AGENT) < nT) {
        __builtin_amdgcn_s_sleep(2);
      }
    }
    __syncthreads();  // off fully published
    const int sb = bid - nT;
    for (int e = sb * 256 + t; e < E; e += SCAT_BLOCKS * 256) {
      const int tg = ei[E + e];
      const int p = off[tg] + atomicAdd(&fill[tg], 1);
      ssrc[p] = ei[e];
    }
    return;
  }
  // ---------------- scan role ----------------
  __shared__ int warpTot[4];
  __shared__ int tileOffS;
  const int b = bid;
  const int base = b * 2048 + t * 8;
  int v[8];
  int s = 0;
#pragma unroll
  for (int j = 0; j < 8; ++j) {
    const int i = base + j;
    v[j] = (i < n) ? deg[i] : 0;
    s += v[j];
  }
  const int l = t & 63, w = t >> 6;
  int inc = s;
#pragma unroll
  for (int d = 1; d < 64; d <<= 1) {
    const int o = __shfl_up(inc, d);
    if (l >= d) inc += o;
  }
  if (l == 63) warpTot[w] = inc;
  __syncthreads();
  const int blockTot = warpTot[0] + warpTot[1] + warpTot[2] + warpTot[3];
  int wo = 0;
  for (int k = 0; k < w; ++k) wo += warpTot[k];
  if (t == 0) {
    __hip_atomic_store(&tileSum[b], blockTot, __ATOMIC_RELEASE,
                       __HIP_MEMORY_SCOPE_AGENT);
    atomicAdd(&cnts[0], 1);
    while (__hip_atomic_load(&cnts[0], __ATOMIC_ACQUIRE,
                             __HIP_MEMORY_SCOPE_AGENT) < nT) {
      __builtin_amdgcn_s_sleep(2);
    }
  }
  __syncthreads();
  int tv = 0;
  if (t < 64) {
    int x2 = (t < b) ? __hip_atomic_load(&tileSum[t], __ATOMIC_ACQUIRE,
                                         __HIP_MEMORY_SCOPE_AGENT)
                     : 0;
#pragma unroll
    for (int d = 1; d < 64; d <<= 1) x2 += __shfl_xor(x2, d);
    tv = x2;
  }
  if (t == 0) tileOffS = tv;
  __syncthreads();
  int ex = tileOffS + wo + (inc - s);
#pragma unroll
  for (int j = 0; j < 8; ++j) {
    const int i = base + j;
    if (i < n) {
      off[i] = ex;
      ex += v[j];
    }
  }
  __threadfence();
  __syncthreads();
  if (t == 0) atomicAdd(&cnts[1], 1);
}

// ---- fused layer-1 tail: bf16-gather agg -> h (LDS) -> h @ W2^T ----
__global__ __launch_bounds__(256) void agg_gemm2(
    const int* __restrict__ off, const int* __restrict__ deg,
    const int* __restrict__ ssrc, const __bf16* __restrict__ yl1,
    const float* __restrict__ yr1, const float* __restrict__ b1,
    const __bf16* __restrict__ WB2, __bf16* __restrict__ yl2,
    float* __restrict__ yr2, int N) {
  __shared__ __bf16 hs[64][40];
  const int tid = threadIdx.x;
  const int nb0 = blockIdx.x * 64;
  const int c = tid & 31, r8 = tid >> 5;

  int stA[8], dgA[8];
#pragma unroll
  for (int j = 0; j < 8; ++j) {
    const int i = nb0 + r8 * 8 + j;
    stA[j] = (i < N) ? off[i] : 0;
    dgA[j] = (i < N) ? deg[i] : 0;
  }
#pragma unroll 1
  for (int j = 0; j < 8; ++j) {
    const int i = nb0 + r8 * 8 + j;
    float hv = 0.0f;
    if (i < N) {
      const int st = stA[j], d = dgA[j];
      float acc = 0.0f;
      int e = 0;
      for (; e + 4 <= d; e += 4) {
        const int s0 = ssrc[st + e + 0];
        const int s1 = ssrc[st + e + 1];
        const int s2 = ssrc[st + e + 2];
        const int s3 = ssrc[st + e + 3];
        acc += (float)yl1[(long)s0 * 32 + c] + (float)yl1[(long)s1 * 32 + c] +
               (float)yl1[(long)s2 * 32 + c] + (float)yl1[(long)s3 * 32 + c];
      }
      for (; e < d; ++e) acc += (float)yl1[(long)ssrc[st + e] * 32 + c];
      hv = acc / fmaxf((float)d, 1.0f) + b1[c] + yr1[(long)i * 32 + c];
    }
    hs[r8 * 8 + j][c] = (__bf16)hv;
  }
  __syncthreads();

  const int w = tid >> 6, l = tid & 63;
  const int lr = l & 15, lg = l >> 4;
  const bf16x8 af = *reinterpret_cast<const bf16x8*>(&hs[w * 16 + lr][lg * 8]);
  f32x4 acc4[4];
#pragma unroll
  for (int j = 0; j < 4; ++j) acc4[j] = (f32x4){0.f, 0.f, 0.f, 0.f};
#pragma unroll
  for (int ct = 0; ct < 4; ++ct) {
    const bf16x8 bf = *reinterpret_cast<const bf16x8*>(
        WB2 + (ct * 16 + lr) * 32 + lg * 8);
    acc4[ct] = __builtin_amdgcn_mfma_f32_16x16x32_bf16(af, bf, acc4[ct], 0, 0, 0);
  }
#pragma unroll
  for (int j = 0; j < 4; ++j) {
    const long R = (long)nb0 + w * 16 + lg * 4 + j;
    if (R < N) {
#pragma unroll
      for (int ct = 0; ct < 2; ++ct)
        yl2[R * 32 + ct * 16 + lr] = (__bf16)acc4[ct][j];
#pragma unroll
      for (int ct = 2; ct < 4; ++ct)
        yr2[R * 32 + (ct - 2) * 16 + lr] = acc4[ct][j];
    }
  }
}

// -------- layer-2 tail: bf16-gather agg + relu + log_softmax --------
__global__ __launch_bounds__(256) void agg_final(
    const int* __restrict__ off, const int* __restrict__ deg,
    const int* __restrict__ ssrc, const __bf16* __restrict__ yl2,
    const float* __restrict__ yr2, const float* __restrict__ bias,
    float* __restrict__ out, int N) {
  const int t = blockIdx.x * 256 + threadIdx.x;
  const int i = t >> 5, c = t & 31;
  if (i >= N) return;
  const int st = off[i], d = deg[i];
  float acc = 0.0f;
  int e = 0;
  for (; e + 4 <= d; e += 4) {
    const int s0 = ssrc[st + e + 0];
    const int s1 = ssrc[st + e + 1];
    const int s2 = ssrc[st + e + 2];
    const int s3 = ssrc[st + e + 3];
    acc += (float)yl2[(long)s0 * 32 + c] + (float)yl2[(long)s1 * 32 + c] +
           (float)yl2[(long)s2 * 32 + c] + (float)yl2[(long)s3 * 32 + c];
  }
  for (; e < d; ++e) acc += (float)yl2[(long)ssrc[st + e] * 32 + c];
  const float mean = acc / fmaxf((float)d, 1.0f);
  float v = mean + bias[c] + yr2[(long)i * 32 + c];
  v = fmaxf(v, 0.0f);
  float m = v;
#pragma unroll
  for (int dd = 16; dd >= 1; dd >>= 1) m = fmaxf(m, __shfl_xor(m, dd));
  const float ex = __expf(v - m);
  float s = ex;
#pragma unroll
  for (int dd = 16; dd >= 1; dd >>= 1) s += __shfl_xor(s, dd);
  out[(long)i * 32 + c] = (v - m) - __logf(s);
}

extern "C" void kernel_launch(void* const* d_in, const int* in_sizes, int n_in,
                              void* d_out, int out_size, void* d_ws,
                              size_t ws_size, hipStream_t stream) {
  const float* x = (const float*)d_in[0];
  const int* ei = (const int*)d_in[1];
  const float* W1l = (const float*)d_in[2];
  const float* b1l = (const float*)d_in[3];
  const float* W1r = (const float*)d_in[4];
  const float* W2l = (const float*)d_in[5];
  const float* b2l = (const float*)d_in[6];
  const float* W2r = (const float*)d_in[7];
  float* out = (float*)d_out;

  const int N = in_sizes[0] / K1;
  const int E = in_sizes[1] / 2;
  const int nTiles = (N + 2047) / 2048;  // 49 at N=100000 (co-resident)

  char* ws = (char*)d_ws;
  size_t o = 0;
  auto alloc = [&](size_t bytes) {
    void* p = ws + o;
    o += (bytes + 255) & ~(size_t)255;
    return p;
  };
  __bf16* yl1 = (__bf16*)alloc((size_t)N * 32 * 2);
  float* yr1 = (float*)alloc((size_t)N * 32 * 4);
  __bf16* yl2 = (__bf16*)alloc((size_t)N * 32 * 2);
  float* yr2 = (float*)alloc((size_t)N * 32 * 4);
  __bf16* wb1 = (__bf16*)alloc((size_t)64 * KP1 * 2);
  __bf16* wb2 = (__bf16*)alloc((size_t)64 * 32 * 2);
  int* deg = (int*)alloc((size_t)(2 * N + 64) * 4);  // deg | fill | cnts
  int* fill = deg + N;
  int* cnts = deg + 2 * N;
  int* off = (int*)alloc((size_t)N * 4);
  int* ssrc = (int*)alloc((size_t)E * 4);
  int* tileSum = (int*)alloc(64 * 4);

  const int zcount = 2 * N + 64;
  const int zBlocks = (zcount + 4095) / 4096;
  conv_zero<<<CONV_BLOCKS + zBlocks, 256, 0, stream>>>(W1l, W1r, W2l, W2r,
                                                       wb1, wb2, deg, zcount);
  const int gemmBlocks = (N + BM - 1) / BM;
  const int histBlocks = (E + 1023) / 1024;
  gemm_big<<<gemmBlocks + histBlocks, 256, 0, stream>>>(
      x, wb1, yl1, yr1, N, gemmBlocks, ei, deg, E);
  csr_build<<<nTiles + SCAT_BLOCKS, 256, 0, stream>>>(
      deg, tileSum, cnts, off, N, nTiles, ei, fill, ssrc, E);
  agg_gemm2<<<(N + 63) / 64, 256, 0, stream>>>(off, deg, ssrc, yl1, yr1, b1l,
                                               wb2, yl2, yr2, N);
  agg_final<<<(N * 32 + 255) / 256, 256, 0, stream>>>(off, deg, ssrc, yl2,
                                                      yr2, b2l, out, N);
}

// Round 19
// 265.271 us; speedup vs baseline: 1.2708x; 1.1008x over previous
//
#include <hip/hip_runtime.h>
#include <hip/hip_bf16.h>

// GraphSAGE 2-layer. FINAL-FORM REVERT: byte-identical to R16 (265.9us best).
// R17 (CSR-in-gemm overlap) and R18 (scan+scatter merge) both regressed ->
// this dispatch structure is the measured optimum of the explored space.
// Ledger: gemm 160us (read-path ceiling; 8 schedule variants within +-10%),
// aggs ~50us (L2 line-touch ceiling), CSR+conv+gaps ~56us.

typedef __attribute__((ext_vector_type(8))) __bf16 bf16x8;
typedef __attribute__((ext_vector_type(4))) float f32x4;

constexpr int K1 = 1433;
constexpr int KP1 = 1536;
constexpr int BK = 32;
constexpr int NS = 45;
constexpr int BM = 128;
constexpr int CONV_BLOCKS = (64 * KP1 + 64 * 32 + 255) / 256;  // 392

__device__ __forceinline__ void gload_lds16(const void* g, void* l) {
  __builtin_amdgcn_global_load_lds(
      reinterpret_cast<const __attribute__((address_space(1))) void*>(
          reinterpret_cast<uintptr_t>(g)),
      reinterpret_cast<__attribute__((address_space(3))) void*>(
          reinterpret_cast<uintptr_t>(l)),
      16, 0, 0);
}

__device__ __forceinline__ bf16x8 cvt8(const float4 lo, const float4 hi) {
  bf16x8 r;
  r[0] = (__bf16)lo.x; r[1] = (__bf16)lo.y;
  r[2] = (__bf16)lo.z; r[3] = (__bf16)lo.w;
  r[4] = (__bf16)hi.x; r[5] = (__bf16)hi.y;
  r[6] = (__bf16)hi.z; r[7] = (__bf16)hi.w;
  return r;
}

// conv blocks convert weights; zero-role blocks clear deg|fill|cnt.
__global__ __launch_bounds__(256) void conv_zero(
    const float* __restrict__ W1l, const float* __restrict__ W1r,
    const float* __restrict__ W2l, const float* __restrict__ W2r,
    __bf16* __restrict__ wb1, __bf16* __restrict__ wb2,
    int* __restrict__ zbuf, int zcount) {
  if ((int)blockIdx.x < CONV_BLOCKS) {
    const int t = blockIdx.x * 256 + threadIdx.x;
    if (t < 64 * KP1) {
      const int c = t / KP1, k = t - c * KP1;
      float v = 0.0f;
      if (k < K1)
        v = (c < 32) ? W1l[(long)c * K1 + k] : W1r[(long)(c - 32) * K1 + k];
      wb1[t] = (__bf16)v;
    } else {
      const int u = t - 64 * KP1;
      if (u < 64 * 32) {
        const int c = u >> 5, k = u & 31;
        const float v = (c < 32) ? W2l[c * 32 + k] : W2r[(c - 32) * 32 + k];
        wb2[u] = (__bf16)v;
      }
    }
  } else {
    const int base = (blockIdx.x - CONV_BLOCKS) * 4096 + threadIdx.x * 16;
#pragma unroll
    for (int j = 0; j < 16; ++j) {
      const int i = base + j;
      if (i < zcount) zbuf[i] = 0;
    }
  }
}

// yl[N][32] (bf16) | yr[N][32] (f32) = X @ WB^T.  (R8 pipeline.)
// Blocks >= gemmBlocks do the degree histogram (hidden under the GEMM).
__global__ __launch_bounds__(256) void gemm_big(const float* __restrict__ X,
                                                const __bf16* __restrict__ WB,
                                                __bf16* __restrict__ yl,
                                                float* __restrict__ yr,
                                                int Nrows, int gemmBlocks,
                                                const int* __restrict__ ei,
                                                int* __restrict__ deg, int E) {
  __shared__ float ldsA[2][BM][BK];
  __shared__ __bf16 ldsB[2][64][BK];
  if ((int)blockIdx.x >= gemmBlocks) {  // ---- hist role ----
    const int base = ((int)blockIdx.x - gemmBlocks) * 1024 + threadIdx.x;
#pragma unroll
    for (int j = 0; j < 4; ++j) {
      const int e = base + j * 256;
      if (e < E) atomicAdd(&deg[ei[E + e]], 1);
    }
    return;
  }
  const int tid = threadIdx.x;
  const int w = tid >> 6, l = tid & 63;
  const int lr = l & 15, lg = l >> 4;
  const int row0 = blockIdx.x * BM;

  const int aRowIn = (l >> 3);
  const int aChunk = (l & 7) ^ aRowIn;
  long aRow[4];
#pragma unroll
  for (int i = 0; i < 4; ++i) {
    long r = (long)row0 + w * 32 + i * 8 + aRowIn;
    if (r >= Nrows) r = Nrows - 1;
    aRow[i] = r;
  }
  const float* const pAmax = X + (size_t)Nrows * K1 - 4;
  const int bRow = w * 16 + (l >> 2);
  const int bChunk = (l & 3) ^ ((l >> 3) & 3);
  const __bf16* const pB0 = WB + (long)bRow * KP1 + bChunk * 8;

  auto stage = [&](int s, int buf) {
    const int k0 = s * BK;
#pragma unroll
    for (int i = 0; i < 4; ++i) {
      const float* g = X + aRow[i] * K1 + k0 + aChunk * 4;
      if (g > pAmax) g = pAmax;
      gload_lds16(g, &ldsA[buf][w * 32 + i * 8][0]);
    }
    gload_lds16(pB0 + k0, &ldsB[buf][w * 16][0]);
  };

  f32x4 acc[2][4];
#pragma unroll
  for (int t = 0; t < 2; ++t)
#pragma unroll
    for (int j = 0; j < 4; ++j) acc[t][j] = (f32x4){0.f, 0.f, 0.f, 0.f};

  const int swzA = lr & 7;
  const int swzB = (lr >> 1) & 3;

  stage(0, 0);
#pragma unroll 1
  for (int s = 0; s < NS; ++s) {
    const int buf = s & 1;
    if (s + 1 < NS) {
      stage(s + 1, buf ^ 1);
      asm volatile("s_waitcnt vmcnt(5)" ::: "memory");
    } else {
      asm volatile("s_waitcnt vmcnt(0)" ::: "memory");
    }
    __builtin_amdgcn_s_barrier();
    __builtin_amdgcn_sched_barrier(0);
    bf16x8 bfrag[4];
#pragma unroll
    for (int ct = 0; ct < 4; ++ct) {
      const int br = ct * 16 + lr;
      bfrag[ct] = *reinterpret_cast<const bf16x8*>(
          &ldsB[buf][br][(lg ^ swzB) * 8]);
    }
#pragma unroll
    for (int t = 0; t < 2; ++t) {
      const int fr = w * 32 + t * 16 + lr;
      const float4 u = *reinterpret_cast<const float4*>(
          &ldsA[buf][fr][((lg * 2 + 0) ^ swzA) * 4]);
      const float4 v = *reinterpret_cast<const float4*>(
          &ldsA[buf][fr][((lg * 2 + 1) ^ swzA) * 4]);
      const bf16x8 af = cvt8(u, v);
#pragma unroll
      for (int ct = 0; ct < 4; ++ct)
        acc[t][ct] =
            __builtin_amdgcn_mfma_f32_16x16x32_bf16(af, bfrag[ct], acc[t][ct], 0, 0, 0);
    }
    __builtin_amdgcn_sched_barrier(0);
    __builtin_amdgcn_s_barrier();
  }

#pragma unroll
  for (int t = 0; t < 2; ++t) {
#pragma unroll
    for (int j = 0; j < 4; ++j) {
      const long R = (long)row0 + w * 32 + t * 16 + lg * 4 + j;
      if (R < Nrows) {
#pragma unroll
        for (int ct = 0; ct < 2; ++ct)
          yl[R * 32 + ct * 16 + lr] = (__bf16)acc[t][ct][j];
#pragma unroll
        for (int ct = 2; ct < 4; ++ct)
          yr[R * 32 + (ct - 2) * 16 + lr] = acc[t][ct][j];
      }
    }
  }
}

// ---- merged tilesum+offsets: 49 co-resident blocks, spin barrier ----
__global__ __launch_bounds__(256) void csr_scan(const int* __restrict__ deg,
                                                int* __restrict__ tileSum,
                                                int* __restrict__ cnt,
                                                int* __restrict__ off, int n,
                                                int nT) {
  __shared__ int warpTot[4];
  __shared__ int tileOffS;
  const int b = blockIdx.x, t = threadIdx.x;
  const int base = b * 2048 + t * 8;
  int v[8];
  int s = 0;
#pragma unroll
  for (int j = 0; j < 8; ++j) {
    const int i = base + j;
    v[j] = (i < n) ? deg[i] : 0;
    s += v[j];
  }
  const int l = t & 63, w = t >> 6;
  int inc = s;
#pragma unroll
  for (int d = 1; d < 64; d <<= 1) {
    const int o = __shfl_up(inc, d);
    if (l >= d) inc += o;
  }
  if (l == 63) warpTot[w] = inc;
  __syncthreads();
  const int blockTot = warpTot[0] + warpTot[1] + warpTot[2] + warpTot[3];
  int wo = 0;
  for (int k = 0; k < w; ++k) wo += warpTot[k];
  if (t == 0) {
    __hip_atomic_store(&tileSum[b], blockTot, __ATOMIC_RELEASE,
                       __HIP_MEMORY_SCOPE_AGENT);
    atomicAdd(cnt, 1);  // device-scope arrive
    while (__hip_atomic_load(cnt, __ATOMIC_ACQUIRE,
                             __HIP_MEMORY_SCOPE_AGENT) < nT) {
    }
  }
  __syncthreads();  // all threads wait for wave-0's spin
  int tv = 0;
  if (t < 64) {
    int x2 = (t < b) ? __hip_atomic_load(&tileSum[t], __ATOMIC_ACQUIRE,
                                         __HIP_MEMORY_SCOPE_AGENT)
                     : 0;
#pragma unroll
    for (int d = 1; d < 64; d <<= 1) x2 += __shfl_xor(x2, d);
    tv = x2;
  }
  if (t == 0) tileOffS = tv;
  __syncthreads();
  int ex = tileOffS + wo + (inc - s);
#pragma unroll
  for (int j = 0; j < 8; ++j) {
    const int i = base + j;
    if (i < n) {
      off[i] = ex;
      ex += v[j];
    }
  }
}

__global__ __launch_bounds__(256) void scatter_src(const int* __restrict__ ei,
                                                   const int* __restrict__ off,
                                                   int* __restrict__ fill,
                                                   int* __restrict__ ssrc,
                                                   int E) {
  const int e = blockIdx.x * 256 + threadIdx.x;
  if (e < E) {
    const int t = ei[E + e];
    const int p = off[t] + atomicAdd(&fill[t], 1);
    ssrc[p] = ei[e];
  }
}

// ---- fused layer-1 tail: bf16-gather agg -> h (LDS) -> h @ W2^T ----
__global__ __launch_bounds__(256) void agg_gemm2(
    const int* __restrict__ off, const int* __restrict__ deg,
    const int* __restrict__ ssrc, const __bf16* __restrict__ yl1,
    const float* __restrict__ yr1, const float* __restrict__ b1,
    const __bf16* __restrict__ WB2, __bf16* __restrict__ yl2,
    float* __restrict__ yr2, int N) {
  __shared__ __bf16 hs[64][40];
  const int tid = threadIdx.x;
  const int nb0 = blockIdx.x * 64;
  const int c = tid & 31, r8 = tid >> 5;

  int stA[8], dgA[8];
#pragma unroll
  for (int j = 0; j < 8; ++j) {
    const int i = nb0 + r8 * 8 + j;
    stA[j] = (i < N) ? off[i] : 0;
    dgA[j] = (i < N) ? deg[i] : 0;
  }
#pragma unroll 1
  for (int j = 0; j < 8; ++j) {
    const int i = nb0 + r8 * 8 + j;
    float hv = 0.0f;
    if (i < N) {
      const int st = stA[j], d = dgA[j];
      float acc = 0.0f;
      int e = 0;
      for (; e + 4 <= d; e += 4) {
        const int s0 = ssrc[st + e + 0];
        const int s1 = ssrc[st + e + 1];
        const int s2 = ssrc[st + e + 2];
        const int s3 = ssrc[st + e + 3];
        acc += (float)yl1[(long)s0 * 32 + c] + (float)yl1[(long)s1 * 32 + c] +
               (float)yl1[(long)s2 * 32 + c] + (float)yl1[(long)s3 * 32 + c];
      }
      for (; e < d; ++e) acc += (float)yl1[(long)ssrc[st + e] * 32 + c];
      hv = acc / fmaxf((float)d, 1.0f) + b1[c] + yr1[(long)i * 32 + c];
    }
    hs[r8 * 8 + j][c] = (__bf16)hv;
  }
  __syncthreads();

  const int w = tid >> 6, l = tid & 63;
  const int lr = l & 15, lg = l >> 4;
  const bf16x8 af = *reinterpret_cast<const bf16x8*>(&hs[w * 16 + lr][lg * 8]);
  f32x4 acc4[4];
#pragma unroll
  for (int j = 0; j < 4; ++j) acc4[j] = (f32x4){0.f, 0.f, 0.f, 0.f};
#pragma unroll
  for (int ct = 0; ct < 4; ++ct) {
    const bf16x8 bf = *reinterpret_cast<const bf16x8*>(
        WB2 + (ct * 16 + lr) * 32 + lg * 8);
    acc4[ct] = __builtin_amdgcn_mfma_f32_16x16x32_bf16(af, bf, acc4[ct], 0, 0, 0);
  }
#pragma unroll
  for (int j = 0; j < 4; ++j) {
    const long R = (long)nb0 + w * 16 + lg * 4 + j;
    if (R < N) {
#pragma unroll
      for (int ct = 0; ct < 2; ++ct)
        yl2[R * 32 + ct * 16 + lr] = (__bf16)acc4[ct][j];
#pragma unroll
      for (int ct = 2; ct < 4; ++ct)
        yr2[R * 32 + (ct - 2) * 16 + lr] = acc4[ct][j];
    }
  }
}

// -------- layer-2 tail: bf16-gather agg + relu + log_softmax --------
__global__ __launch_bounds__(256) void agg_final(
    const int* __restrict__ off, const int* __restrict__ deg,
    const int* __restrict__ ssrc, const __bf16* __restrict__ yl2,
    const float* __restrict__ yr2, const float* __restrict__ bias,
    float* __restrict__ out, int N) {
  const int t = blockIdx.x * 256 + threadIdx.x;
  const int i = t >> 5, c = t & 31;
  if (i >= N) return;
  const int st = off[i], d = deg[i];
  float acc = 0.0f;
  int e = 0;
  for (; e + 4 <= d; e += 4) {
    const int s0 = ssrc[st + e + 0];
    const int s1 = ssrc[st + e + 1];
    const int s2 = ssrc[st + e + 2];
    const int s3 = ssrc[st + e + 3];
    acc += (float)yl2[(long)s0 * 32 + c] + (float)yl2[(long)s1 * 32 + c] +
           (float)yl2[(long)s2 * 32 + c] + (float)yl2[(long)s3 * 32 + c];
  }
  for (; e < d; ++e) acc += (float)yl2[(long)ssrc[st + e] * 32 + c];
  const float mean = acc / fmaxf((float)d, 1.0f);
  float v = mean + bias[c] + yr2[(long)i * 32 + c];
  v = fmaxf(v, 0.0f);
  float m = v;
#pragma unroll
  for (int dd = 16; dd >= 1; dd >>= 1) m = fmaxf(m, __shfl_xor(m, dd));
  const float ex = __expf(v - m);
  float s = ex;
#pragma unroll
  for (int dd = 16; dd >= 1; dd >>= 1) s += __shfl_xor(s, dd);
  out[(long)i * 32 + c] = (v - m) - __logf(s);
}

extern "C" void kernel_launch(void* const* d_in, const int* in_sizes, int n_in,
                              void* d_out, int out_size, void* d_ws,
                              size_t ws_size, hipStream_t stream) {
  const float* x = (const float*)d_in[0];
  const int* ei = (const int*)d_in[1];
  const float* W1l = (const float*)d_in[2];
  const float* b1l = (const float*)d_in[3];
  const float* W1r = (const float*)d_in[4];
  const float* W2l = (const float*)d_in[5];
  const float* b2l = (const float*)d_in[6];
  const float* W2r = (const float*)d_in[7];
  float* out = (float*)d_out;

  const int N = in_sizes[0] / K1;
  const int E = in_sizes[1] / 2;
  const int nTiles = (N + 2047) / 2048;  // 49 at N=100000 (co-resident)

  char* ws = (char*)d_ws;
  size_t o = 0;
  auto alloc = [&](size_t bytes) {
    void* p = ws + o;
    o += (bytes + 255) & ~(size_t)255;
    return p;
  };
  __bf16* yl1 = (__bf16*)alloc((size_t)N * 32 * 2);
  float* yr1 = (float*)alloc((size_t)N * 32 * 4);
  __bf16* yl2 = (__bf16*)alloc((size_t)N * 32 * 2);
  float* yr2 = (float*)alloc((size_t)N * 32 * 4);
  __bf16* wb1 = (__bf16*)alloc((size_t)64 * KP1 * 2);
  __bf16* wb2 = (__bf16*)alloc((size_t)64 * 32 * 2);
  int* deg = (int*)alloc((size_t)(2 * N + 64) * 4);  // deg | fill | cnt
  int* fill = deg + N;
  int* cnt = deg + 2 * N;
  int* off = (int*)alloc((size_t)N * 4);
  int* ssrc = (int*)alloc((size_t)E * 4);
  int* tileSum = (int*)alloc(64 * 4);

  const int zcount = 2 * N + 64;
  const int zBlocks = (zcount + 4095) / 4096;
  conv_zero<<<CONV_BLOCKS + zBlocks, 256, 0, stream>>>(W1l, W1r, W2l, W2r,
                                                       wb1, wb2, deg, zcount);
  const int gemmBlocks = (N + BM - 1) / BM;
  const int histBlocks = (E + 1023) / 1024;
  gemm_big<<<gemmBlocks + histBlocks, 256, 0, stream>>>(
      x, wb1, yl1, yr1, N, gemmBlocks, ei, deg, E);
  csr_scan<<<nTiles, 256, 0, stream>>>(deg, tileSum, cnt, off, N, nTiles);
  scatter_src<<<(E + 255) / 256, 256, 0, stream>>>(ei, off, fill, ssrc, E);
  agg_gemm2<<<(N + 63) / 64, 256, 0, stream>>>(off, deg, ssrc, yl1, yr1, b1l,
                                               wb2, yl2, yr2, N);
  agg_final<<<(N * 32 + 255) / 256, 256, 0, stream>>>(off, deg, ssrc, yl2,
                                                      yr2, b2l, out, N);
}